// Round 5
// baseline (284.407 us; speedup 1.0000x reference)
//
#include <hip/hip_runtime.h>
#include <hip/hip_bf16.h>

// MHA forward: b=2, t=2048, d=1024, h=16, n=64. Inputs/outputs FLOAT32.
// ws (u16, 33.55 MB total — round-2-proven size):
//   Wkb|Wqb|Wvb|Wob (1048576 ea) | Kp (4194304) | Qp (4194304, doubles as Op) |
//   Vt (4194304, per-head transposed [bh][64 d][2048 t])

typedef unsigned short u16;
typedef unsigned int   u32;
using short8 = __attribute__((ext_vector_type(8))) short;
using f32x4  = __attribute__((ext_vector_type(4))) float;

__device__ __forceinline__ u16 f2b(float f) {
    u32 u = __float_as_uint(f);
    u += 0x7FFFu + ((u >> 16) & 1u);
    return (u16)(u >> 16);
}
__device__ __forceinline__ u32 pack2(float lo, float hi) {
    union { __hip_bfloat162 h; u32 u; } c;
    c.h = __float22bfloat162_rn(make_float2(lo, hi));
    return c.u;
}
__device__ __forceinline__ uint4 stage8(const float* p) {
    float4 a = *(const float4*)p;
    float4 b = *(const float4*)(p + 4);
    uint4 v;
    v.x = pack2(a.x, a.y); v.y = pack2(a.z, a.w);
    v.z = pack2(b.x, b.y); v.w = pack2(b.z, b.w);
    return v;
}
__device__ __forceinline__ void gld_lds16(const u16* g, u16* l) {
    __builtin_amdgcn_global_load_lds(
        (const __attribute__((address_space(1))) void*)g,
        (__attribute__((address_space(3))) void*)l, 16, 0, 0);
}

// ---------------------------------------------------------------------------
// weights fp32 -> bf16 (4 x 1M elems). grid (1024, 4) x 256.
// ---------------------------------------------------------------------------
__global__ __launch_bounds__(256) void convert_w_kernel(
    const float* s0, const float* s1, const float* s2, const float* s3,
    u16* d0, u16* d1, u16* d2, u16* d3)
{
    const float* s; u16* d;
    switch (blockIdx.y) {
        case 0: s = s0; d = d0; break;
        case 1: s = s1; d = d1; break;
        case 2: s = s2; d = d2; break;
        default: s = s3; d = d3; break;
    }
    const u32 i = blockIdx.x * 256 + threadIdx.x;   // < 262144 float4s
    float4 f = ((const float4*)s)[i];
    uint2 o; o.x = pack2(f.x, f.y); o.y = pack2(f.z, f.w);
    ((uint2*)d)[i] = o;
}

// ---------------------------------------------------------------------------
// GEMM epilogues. MODE 0: u16 row-major. MODE 1: u16 per-head transposed Vt.
// MODE 2: f32 row-major + bias.
// ---------------------------------------------------------------------------
template <int MODE>
__device__ __forceinline__ void gemm_epilogue(
    f32x4 (&acc)[4][4], void* __restrict__ C, const float* __restrict__ bias,
    float scale, u32 bm, u32 bn, int wr, int wc, int ml, int g)
{
    constexpr u32 N = 1024;
    if (MODE == 1) {
        const u32 bb = bm >> 11;
#pragma unroll
        for (int ct = 0; ct < 4; ++ct) {
            const u32 col = bn + wc * 64 + ct * 16 + ml;
            const u32 cb = ((bb * 16 + (col >> 6)) * 64 + (col & 63)) * 2048;
#pragma unroll
            for (int it = 0; it < 4; ++it) {
                const u32 trow = (bm & 2047) + wr * 64 + it * 16 + g * 4;
                ((u32*)C)[(cb + trow) >> 1]     = pack2(acc[it][ct][0], acc[it][ct][1]);
                ((u32*)C)[(cb + trow + 2) >> 1] = pack2(acc[it][ct][2], acc[it][ct][3]);
            }
        }
    } else {
#pragma unroll
        for (int ct = 0; ct < 4; ++ct) {
            const u32 col = bn + wc * 64 + ct * 16 + ml;
            const float bv = bias ? bias[col] : 0.0f;
#pragma unroll
            for (int it = 0; it < 4; ++it) {
                const u32 row = bm + wr * 64 + it * 16 + g * 4;
#pragma unroll
                for (int r = 0; r < 4; ++r) {
                    const float v = acc[it][ct][r] * scale + bv;
                    if (MODE == 2) ((float*)C)[(size_t)(row + r) * N + col] = v;
                    else           ((u16*)C)[(size_t)(row + r) * N + col] = f2b(v);
                }
            }
        }
    }
}

// ---------------------------------------------------------------------------
// PROJ GEMM: A fp32 (VGPR-convert into padded LDS, conflict-free A-frag reads),
// W bf16 via global_load_lds. C = A @ W^T, M=4096, N=K=1024, 128x128 tile.
// ---------------------------------------------------------------------------
template <int MODE>
__device__ __forceinline__ void gemm_proj(
    const float* __restrict__ A, const u16* __restrict__ W,
    void* __restrict__ C, float scale)
{
    constexpr u32 K = 1024;
    __shared__ u16 As[128 * 40];   // padded: stride 40 u16 (80 B, 16B-aligned)
    __shared__ u16 Bs[128 * 32];   // unpadded (global_load_lds)

    const int tid  = threadIdx.x;
    const int lane = tid & 63;
    const int w    = tid >> 6;
    const int wr   = w >> 1, wc = w & 1;
    const int ml   = lane & 15, g = lane >> 4;
    const u32 bm   = blockIdx.y * 128, bn = blockIdx.x * 128;

    f32x4 acc[4][4] = {};

    // A staging: r0 = tid>>1 (0..127), hh = tid&1 -> k halves 0..15 / 16..31
    const u32 r0 = tid >> 1, hh = tid & 1;
    const float* gA = A + (size_t)(bm + r0) * K + hh * 16;
    u16* lA = &As[r0 * 40 + hh * 16];

    // W staging: wave w rows w*32..+31 via gld_lds
    const u16* gB = W + (size_t)(bn + w * 32 + (lane >> 2)) * K + (lane & 3) * 8;
    u16* lB = &Bs[w * 1024];

    for (u32 k0 = 0; k0 < K; k0 += 32) {
        __syncthreads();
        *(uint4*)lA       = stage8(gA + k0);
        *(uint4*)(lA + 8) = stage8(gA + k0 + 8);
        gld_lds16(gB + k0, lB);
        gld_lds16(gB + 16 * K + k0, lB + 512);
        __syncthreads();

        short8 af[4], bf[4];
#pragma unroll
        for (int it = 0; it < 4; ++it)
            af[it] = *(const short8*)&As[(wr * 64 + it * 16 + ml) * 40 + g * 8];
#pragma unroll
        for (int ct = 0; ct < 4; ++ct)
            bf[ct] = *(const short8*)&Bs[(wc * 64 + ct * 16 + ml) * 32 + g * 8];
#pragma unroll
        for (int it = 0; it < 4; ++it)
#pragma unroll
            for (int ct = 0; ct < 4; ++ct)
                acc[it][ct] = __builtin_amdgcn_mfma_f32_16x16x32_bf16(
                    af[it], bf[ct], acc[it][ct], 0, 0, 0);
    }
    gemm_epilogue<MODE>(acc, C, nullptr, scale, bm, bn, wr, wc, ml, g);
}

__global__ __launch_bounds__(256) void proj3_kernel(
    const float* kin, const float* qin, const float* vin,
    const u16* Wkb, const u16* Wqb, const u16* Wvb,
    u16* Kp, u16* Qp, u16* Vt)
{
    if (blockIdx.z == 0)      gemm_proj<0>(kin, Wkb, Kp, 1.0f);
    else if (blockIdx.z == 1) gemm_proj<0>(qin, Wqb, Qp, 0.18033688011112042f);
    else                      gemm_proj<1>(vin, Wvb, Vt, 1.0f);
}

// ---------------------------------------------------------------------------
// OUT GEMM: pure bf16 m97-style (A and W via global_load_lds), fp32 out + bias.
// ---------------------------------------------------------------------------
__global__ __launch_bounds__(256) void out_gemm_kernel(
    const u16* __restrict__ A, const u16* __restrict__ W,
    float* __restrict__ C, const float* __restrict__ bias)
{
    constexpr u32 K = 1024;
    __shared__ u16 As[128 * 32];
    __shared__ u16 Bs[128 * 32];

    const int tid  = threadIdx.x;
    const int lane = tid & 63;
    const int w    = tid >> 6;
    const int wr   = w >> 1, wc = w & 1;
    const int ml   = lane & 15, g = lane >> 4;
    const u32 bm   = blockIdx.y * 128, bn = blockIdx.x * 128;

    f32x4 acc[4][4] = {};

    const u32 srow = w * 32 + (lane >> 2), scol = (lane & 3) * 8;
    const u16* gA = A + (size_t)(bm + srow) * K + scol;
    const u16* gB = W + (size_t)(bn + srow) * K + scol;
    u16* lA = &As[w * 1024];
    u16* lB = &Bs[w * 1024];

    for (u32 k0 = 0; k0 < K; k0 += 32) {
        __syncthreads();
        gld_lds16(gA + k0, lA);
        gld_lds16(gA + 16 * K + k0, lA + 512);
        gld_lds16(gB + k0, lB);
        gld_lds16(gB + 16 * K + k0, lB + 512);
        __syncthreads();

        short8 af[4], bf[4];
#pragma unroll
        for (int it = 0; it < 4; ++it)
            af[it] = *(const short8*)&As[(wr * 64 + it * 16 + ml) * 32 + g * 8];
#pragma unroll
        for (int ct = 0; ct < 4; ++ct)
            bf[ct] = *(const short8*)&Bs[(wc * 64 + ct * 16 + ml) * 32 + g * 8];
#pragma unroll
        for (int it = 0; it < 4; ++it)
#pragma unroll
            for (int ct = 0; ct < 4; ++ct)
                acc[it][ct] = __builtin_amdgcn_mfma_f32_16x16x32_bf16(
                    af[it], bf[ct], acc[it][ct], 0, 0, 0);
    }
    gemm_epilogue<2>(acc, C, bias, 1.0f, bm, bn, wr, wc, ml, g);
}

// ---------------------------------------------------------------------------
// Flash attention, s-partitioned waves. Block = (bh, 64 q). Iter = 128 s.
// Wave w owns s-slice w*16+0..15 of each 64-s half-tile; Q B-frags hoisted.
// S^T = K Q^T (C-layout: s=g*4+r, q=ml). no-max softmax; per-wave partial
// O^T accumulated over the wave's s-slices; cross-wave O/l reduce at end.
// P strip per wave: [q][k=32] stride 32 u16, XOR-swizzled (conflict-free reads).
// LDS: Ks 128x72 | Vts 64x136 | QP = max(Qs 64x72, P 4x64x32) = 51 KB.
// ---------------------------------------------------------------------------
__global__ __launch_bounds__(256) void attn_kernel(
    const u16* __restrict__ Qp, const u16* __restrict__ Kp,
    const u16* __restrict__ Vt, u16* __restrict__ Op)
{
    constexpr u32 T = 2048, D = 1024;
    __shared__ u16 pool[26112];
    u16* Ks  = pool;            // [s 0..127][d 0..63], stride 72
    u16* Vts = pool + 9216;     // [d 0..63][s 0..127], stride 136
    u16* QP  = pool + 17920;    // Qs [64][72] then P strips 4 x [64][32]

    const int tid  = threadIdx.x;
    const int lane = tid & 63;
    const int w    = tid >> 6;
    const int ml   = lane & 15;
    const int g    = lane >> 4;
    const u32 bh   = blockIdx.y;
    const u32 b    = bh >> 4, h = bh & 15;
    const u32 t0   = blockIdx.x * 64;

    const u32 base  = b * T * D + h * 64;
    const u32 vbase = bh * 64 * 2048;

    // ---- stage Q (64 q x 64 d) into QP, hoist B-frags ----
    {
        const u32 qr = tid >> 3, cc = tid & 7;
        const u32 go = base + (t0 + qr) * D + cc * 8;
        *(uint4*)&QP[qr * 72 + cc * 8]        = *(const uint4*)&Qp[go];
        *(uint4*)&QP[(qr + 32) * 72 + cc * 8] = *(const uint4*)&Qp[go + 32 * D];
    }
    __syncthreads();
    short8 bq[4][2];
#pragma unroll
    for (int qt = 0; qt < 4; ++qt) {
        bq[qt][0] = *(const short8*)&QP[(qt * 16 + ml) * 72 + g * 8];
        bq[qt][1] = *(const short8*)&QP[(qt * 16 + ml) * 72 + 32 + g * 8];
    }

    f32x4 oacc[4][4] = {};          // [dt][qt]: O^T[d=dt*16+g*4+r][q=qt*16+ml]
    float l4[4] = {};               // per-lane partial denominator per qt

    u16* Pst = &QP[w * 2048];       // wave strip [q][32]
    u32* Pst32 = (u32*)Pst;
    const int swz_w = (ml >> 1) & 3;            // write-side swizzle (q=qt*16+ml)

    // staging indices
    const u32 kr = tid >> 3, kcc = tid & 7;     // Ks rows
    const u32 vd = tid >> 2, vsc = tid & 3;     // Vts rows

    u32 kOff = base + kr * D + kcc * 8;         // += 128*D per iter
    u32 vOff = vbase + vd * 2048 + vsc * 32;    // += 128 per iter

    for (int it = 0; it < 16; ++it) {
        __syncthreads();
        // stage K: 128 s x 64 d
#pragma unroll
        for (int j = 0; j < 4; ++j)
            *(uint4*)&Ks[(kr + j * 32) * 72 + kcc * 8] =
                *(const uint4*)&Kp[kOff + j * 32 * D];
        // stage V^T: 64 d x 128 s
#pragma unroll
        for (int j = 0; j < 4; ++j)
            *(uint4*)&Vts[vd * 136 + vsc * 32 + j * 8] =
                *(const uint4*)&Vt[vOff + j * 8];
        kOff += 128 * D;
        vOff += 128;
        __syncthreads();

        // ---- two 64-s half-tiles: QK^T + softmax + P store ----
#pragma unroll
        for (int hf = 0; hf < 2; ++hf) {
            short8 ka0 = *(const short8*)&Ks[(hf * 64 + w * 16 + ml) * 72 + g * 8];
            short8 ka1 = *(const short8*)&Ks[(hf * 64 + w * 16 + ml) * 72 + 32 + g * 8];
            const int Qd0 = hf * 2 + (g >> 1);
            const u32 pbase = ml * 16 + (u32)(((Qd0 ^ swz_w) << 2) | ((g & 1) << 1));
#pragma unroll
            for (int qt = 0; qt < 4; ++qt) {
                f32x4 z = {};
                z = __builtin_amdgcn_mfma_f32_16x16x32_bf16(ka0, bq[qt][0], z, 0, 0, 0);
                z = __builtin_amdgcn_mfma_f32_16x16x32_bf16(ka1, bq[qt][1], z, 0, 0, 0);
                float p0 = exp2f(z[0]), p1 = exp2f(z[1]);
                float p2 = exp2f(z[2]), p3 = exp2f(z[3]);
                l4[qt] += (p0 + p1) + (p2 + p3);
                Pst32[qt * 256 + pbase]     = pack2(p0, p1);
                Pst32[qt * 256 + pbase + 1] = pack2(p2, p3);
            }
        }

        // ---- PV: O^T += V^T(slice) @ P^T, k=32 over wave's s-slices ----
        short8 pb[4];
#pragma unroll
        for (int qt = 0; qt < 4; ++qt) {
            const u32 q = qt * 16 + ml;
            pb[qt] = *(const short8*)&Pst[q * 32 + ((g ^ ((q >> 1) & 3)) * 8)];
        }
#pragma unroll
        for (int dt = 0; dt < 4; ++dt) {
            short8 va = *(const short8*)&Vts[(dt * 16 + ml) * 136 +
                                             (g >> 1) * 64 + w * 16 + (g & 1) * 8];
#pragma unroll
            for (int qt = 0; qt < 4; ++qt)
                oacc[dt][qt] = __builtin_amdgcn_mfma_f32_16x16x32_bf16(
                    va, pb[qt], oacc[dt][qt], 0, 0, 0);
        }
    }

    // ---- cross-wave reduction ----
    __syncthreads();
    float* R0 = (float*)pool;
    float* R1 = R0 + 4096;
    float* Lr = R1 + 4096;          // 4 x 64

    // l: reduce over g within wave, publish per wave
#pragma unroll
    for (int qt = 0; qt < 4; ++qt) {
        l4[qt] += __shfl_xor(l4[qt], 16);
        l4[qt] += __shfl_xor(l4[qt], 32);
    }
    if (g == 0) {
#pragma unroll
        for (int qt = 0; qt < 4; ++qt) Lr[w * 64 + qt * 16 + ml] = l4[qt];
    }

#define WRITE_R(Rp)                                                          \
    {_Pragma("unroll") for (int dt = 0; dt < 4; ++dt)                        \
     _Pragma("unroll") for (int qt = 0; qt < 4; ++qt)                        \
     _Pragma("unroll") for (int r = 0; r < 4; ++r)                           \
        (Rp)[(dt * 16 + g * 4 + r) * 64 + qt * 16 + ml] = oacc[dt][qt][r];}
#define ADD_R(Rp)                                                            \
    {_Pragma("unroll") for (int dt = 0; dt < 4; ++dt)                        \
     _Pragma("unroll") for (int qt = 0; qt < 4; ++qt)                        \
     _Pragma("unroll") for (int r = 0; r < 4; ++r)                           \
        oacc[dt][qt][r] += (Rp)[(dt * 16 + g * 4 + r) * 64 + qt * 16 + ml];}

    if (w == 1) WRITE_R(R0)
    if (w == 3) WRITE_R(R1)
    __syncthreads();
    if (w == 0) ADD_R(R0)
    if (w == 2) ADD_R(R1)
    __syncthreads();
    if (w == 2) WRITE_R(R0)
    __syncthreads();
    if (w == 0) {
        ADD_R(R0)
#pragma unroll
        for (int qt = 0; qt < 4; ++qt) {
            const u32 q = qt * 16 + ml;
            const float inv = 1.0f / (Lr[q] + Lr[64 + q] + Lr[128 + q] + Lr[192 + q]);
            const u32 row = (b * T + t0 + q) * D + h * 64;
#pragma unroll
            for (int dt = 0; dt < 4; ++dt) {
                const u32 ci = row + dt * 16 + g * 4;
                *(u32*)&Op[ci]     = pack2(oacc[dt][qt][0] * inv, oacc[dt][qt][1] * inv);
                *(u32*)&Op[ci + 2] = pack2(oacc[dt][qt][2] * inv, oacc[dt][qt][3] * inv);
            }
        }
    }
#undef WRITE_R
#undef ADD_R
}

extern "C" void kernel_launch(void* const* d_in, const int* in_sizes, int n_in,
                              void* d_out, int out_size, void* d_ws, size_t ws_size,
                              hipStream_t stream)
{
    const float* kin = (const float*)d_in[0];
    const float* qin = (const float*)d_in[1];
    const float* vin = (const float*)d_in[2];
    const float* Wk  = (const float*)d_in[3];
    const float* Wq  = (const float*)d_in[4];
    const float* Wv  = (const float*)d_in[5];
    const float* Wo  = (const float*)d_in[6];
    const float* bo  = (const float*)d_in[7];
    float* out = (float*)d_out;

    u16* Wkb = (u16*)d_ws;
    u16* Wqb = Wkb + 1048576;
    u16* Wvb = Wqb + 1048576;
    u16* Wob = Wvb + 1048576;
    u16* Kp  = Wob + 1048576;
    u16* Qp  = Kp + 4194304;    // doubles as Op (block-exclusive region reuse)
    u16* Vt  = Qp + 4194304;

    convert_w_kernel<<<dim3(1024, 4), 256, 0, stream>>>(
        Wk, Wq, Wv, Wo, Wkb, Wqb, Wvb, Wob);
    proj3_kernel<<<dim3(8, 32, 3), 256, 0, stream>>>(
        kin, qin, vin, Wkb, Wqb, Wvb, Kp, Qp, Vt);
    attn_kernel<<<dim3(32, 32), 256, 0, stream>>>(Qp, Kp, Vt, Qp);
    out_gemm_kernel<<<dim3(8, 32), 256, 0, stream>>>(Qp, Wob, out, bo);
}

// Round 6
// 265.303 us; speedup vs baseline: 1.0720x; 1.0720x over previous
//
#include <hip/hip_runtime.h>
#include <hip/hip_bf16.h>

// MHA forward: b=2, t=2048, d=1024, h=16, n=64. Inputs/outputs FLOAT32.
// Convert everything to bf16 once; pure-bf16 GEMMs with global_load_lds and
// XOR-swizzled LDS (kills the 8-way stride-32 bank conflict); round-5 attn.
// ws (u16, 58.7 MB, proven by round 4): kb|qb|vb (4194304 ea) |
//   Wkb|Wqb|Wvb|Wob (1048576 ea) | Kp|Qp|Vt (4194304 ea) | Op aliases kb.

typedef unsigned short u16;
typedef unsigned int   u32;
using short8 = __attribute__((ext_vector_type(8))) short;
using f32x4  = __attribute__((ext_vector_type(4))) float;

__device__ __forceinline__ u16 f2b(float f) {
    u32 u = __float_as_uint(f);
    u += 0x7FFFu + ((u >> 16) & 1u);
    return (u16)(u >> 16);
}
__device__ __forceinline__ u32 pack2(float lo, float hi) {
    union { __hip_bfloat162 h; u32 u; } c;
    c.h = __float22bfloat162_rn(make_float2(lo, hi));
    return c.u;
}
__device__ __forceinline__ void gld_lds16(const u16* g, u16* l) {
    __builtin_amdgcn_global_load_lds(
        (const __attribute__((address_space(1))) void*)g,
        (__attribute__((address_space(3))) void*)l, 16, 0, 0);
}

// ---------------------------------------------------------------------------
// fp32 -> bf16 convert. grid (1024, 7): y 0..2 = k,q,v (1048576 float4),
// y 3..6 = Wk,Wq,Wv,Wo (262144 float4).
// ---------------------------------------------------------------------------
__global__ __launch_bounds__(256) void convert_kernel(
    const float* s0, const float* s1, const float* s2, const float* s3,
    const float* s4, const float* s5, const float* s6,
    u16* d0, u16* d1, u16* d2, u16* d3, u16* d4, u16* d5, u16* d6)
{
    const int y = blockIdx.y;
    const float* s; u16* d; u32 n;
    switch (y) {
        case 0: s = s0; d = d0; n = 1048576; break;
        case 1: s = s1; d = d1; n = 1048576; break;
        case 2: s = s2; d = d2; n = 1048576; break;
        case 3: s = s3; d = d3; n = 262144; break;
        case 4: s = s4; d = d4; n = 262144; break;
        case 5: s = s5; d = d5; n = 262144; break;
        default: s = s6; d = d6; n = 262144; break;
    }
    for (u32 i = blockIdx.x * 256 + threadIdx.x; i < n; i += 256 * 1024) {
        float4 f = ((const float4*)s)[i];
        uint2 o; o.x = pack2(f.x, f.y); o.y = pack2(f.z, f.w);
        ((uint2*)d)[i] = o;
    }
}

// ---------------------------------------------------------------------------
// GEMM epilogues. MODE 0: u16 row-major. MODE 1: u16 per-head transposed Vt.
// MODE 2: f32 row-major + bias.
// ---------------------------------------------------------------------------
template <int MODE>
__device__ __forceinline__ void gemm_epilogue(
    f32x4 (&acc)[4][4], void* __restrict__ C, const float* __restrict__ bias,
    float scale, u32 bm, u32 bn, int wr, int wc, int ml, int g)
{
    constexpr u32 N = 1024;
    if (MODE == 1) {
        const u32 bb = bm >> 11;
#pragma unroll
        for (int ct = 0; ct < 4; ++ct) {
            const u32 col = bn + wc * 64 + ct * 16 + ml;
            const u32 cb = ((bb * 16 + (col >> 6)) * 64 + (col & 63)) * 2048;
#pragma unroll
            for (int it = 0; it < 4; ++it) {
                const u32 trow = (bm & 2047) + wr * 64 + it * 16 + g * 4;
                ((u32*)C)[(cb + trow) >> 1]     = pack2(acc[it][ct][0], acc[it][ct][1]);
                ((u32*)C)[(cb + trow + 2) >> 1] = pack2(acc[it][ct][2], acc[it][ct][3]);
            }
        }
    } else {
#pragma unroll
        for (int ct = 0; ct < 4; ++ct) {
            const u32 col = bn + wc * 64 + ct * 16 + ml;
            const float bv = bias ? bias[col] : 0.0f;
#pragma unroll
            for (int it = 0; it < 4; ++it) {
                const u32 row = bm + wr * 64 + it * 16 + g * 4;
#pragma unroll
                for (int r = 0; r < 4; ++r) {
                    const float v = acc[it][ct][r] * scale + bv;
                    if (MODE == 2) ((float*)C)[(size_t)(row + r) * N + col] = v;
                    else           ((u16*)C)[(size_t)(row + r) * N + col] = f2b(v);
                }
            }
        }
    }
}

// ---------------------------------------------------------------------------
// FAST GEMM: pure bf16, global_load_lds staging into XOR-swizzled unpadded
// 128x32 tiles. Swizzle: LDS chunk c of row r holds global chunk c^((r>>1)&3).
// Write side: lane l (row r=l>>2, lds chunk l&3) loads global chunk
// (l&3)^((l>>3)&3). Read side: row ml frag chunk g lives at c=g^((ml>>1)&3).
// Bank pattern 2-way (free) instead of 8-way (2.94x).
// ---------------------------------------------------------------------------
template <int MODE>
__device__ __forceinline__ void gemm_fast(
    const u16* __restrict__ A, const u16* __restrict__ W,
    void* __restrict__ C, const float* __restrict__ bias, float scale)
{
    constexpr u32 K = 1024;
    __shared__ u16 As[128 * 32];
    __shared__ u16 Bs[128 * 32];

    const int tid  = threadIdx.x;
    const int lane = tid & 63;
    const int w    = tid >> 6;
    const int wr   = w >> 1, wc = w & 1;
    const int ml   = lane & 15, g = lane >> 4;
    const u32 bm   = blockIdx.y * 128, bn = blockIdx.x * 128;

    f32x4 acc[4][4] = {};

    // staging: wave w rows w*32..+31, swizzled global column per lane
    const u32 srow = w * 32 + (lane >> 2);
    const u32 scol = (u32)(((lane & 3) ^ ((lane >> 3) & 3)) * 8);
    const u16* gA = A + (size_t)(bm + srow) * K + scol;
    const u16* gB = W + (size_t)(bn + srow) * K + scol;
    u16* lA = &As[w * 1024];
    u16* lB = &Bs[w * 1024];

    // fragment-read swizzled chunk offset (lane-constant)
    const u32 fsw = (u32)((g ^ ((ml >> 1) & 3)) * 8);

    for (u32 k0 = 0; k0 < K; k0 += 32) {
        __syncthreads();
        gld_lds16(gA + k0, lA);
        gld_lds16(gA + 16 * K + k0, lA + 512);
        gld_lds16(gB + k0, lB);
        gld_lds16(gB + 16 * K + k0, lB + 512);
        __syncthreads();

        short8 af[4], bf[4];
#pragma unroll
        for (int it = 0; it < 4; ++it)
            af[it] = *(const short8*)&As[(wr * 64 + it * 16 + ml) * 32 + fsw];
#pragma unroll
        for (int ct = 0; ct < 4; ++ct)
            bf[ct] = *(const short8*)&Bs[(wc * 64 + ct * 16 + ml) * 32 + fsw];
#pragma unroll
        for (int it = 0; it < 4; ++it)
#pragma unroll
            for (int ct = 0; ct < 4; ++ct)
                acc[it][ct] = __builtin_amdgcn_mfma_f32_16x16x32_bf16(
                    af[it], bf[ct], acc[it][ct], 0, 0, 0);
    }
    gemm_epilogue<MODE>(acc, C, bias, scale, bm, bn, wr, wc, ml, g);
}

__global__ __launch_bounds__(256) void proj3_kernel(
    const u16* kb, const u16* qb, const u16* vb,
    const u16* Wkb, const u16* Wqb, const u16* Wvb,
    u16* Kp, u16* Qp, u16* Vt)
{
    if (blockIdx.z == 0)      gemm_fast<0>(kb, Wkb, Kp, nullptr, 1.0f);
    else if (blockIdx.z == 1) gemm_fast<0>(qb, Wqb, Qp, nullptr, 0.18033688011112042f);
    else                      gemm_fast<1>(vb, Wvb, Vt, nullptr, 1.0f);
}

__global__ __launch_bounds__(256) void out_gemm_kernel(
    const u16* A, const u16* W, float* C, const float* bias)
{
    gemm_fast<2>(A, W, C, bias, 1.0f);
}

// ---------------------------------------------------------------------------
// Flash attention (unchanged from round 5): s-partitioned waves, 128-s iter,
// no-max softmax, swizzled P strips, cross-wave O/l reduction.
// ---------------------------------------------------------------------------
__global__ __launch_bounds__(256) void attn_kernel(
    const u16* __restrict__ Qp, const u16* __restrict__ Kp,
    const u16* __restrict__ Vt, u16* __restrict__ Op)
{
    constexpr u32 T = 2048, D = 1024;
    __shared__ u16 pool[26112];
    u16* Ks  = pool;            // [s 0..127][d 0..63], stride 72
    u16* Vts = pool + 9216;     // [d 0..63][s 0..127], stride 136
    u16* QP  = pool + 17920;    // Qs [64][72] then P strips 4 x [64][32]

    const int tid  = threadIdx.x;
    const int lane = tid & 63;
    const int w    = tid >> 6;
    const int ml   = lane & 15;
    const int g    = lane >> 4;
    const u32 bh   = blockIdx.y;
    const u32 b    = bh >> 4, h = bh & 15;
    const u32 t0   = blockIdx.x * 64;

    const u32 base  = b * T * D + h * 64;
    const u32 vbase = bh * 64 * 2048;

    {
        const u32 qr = tid >> 3, cc = tid & 7;
        const u32 go = base + (t0 + qr) * D + cc * 8;
        *(uint4*)&QP[qr * 72 + cc * 8]        = *(const uint4*)&Qp[go];
        *(uint4*)&QP[(qr + 32) * 72 + cc * 8] = *(const uint4*)&Qp[go + 32 * D];
    }
    __syncthreads();
    short8 bq[4][2];
#pragma unroll
    for (int qt = 0; qt < 4; ++qt) {
        bq[qt][0] = *(const short8*)&QP[(qt * 16 + ml) * 72 + g * 8];
        bq[qt][1] = *(const short8*)&QP[(qt * 16 + ml) * 72 + 32 + g * 8];
    }

    f32x4 oacc[4][4] = {};
    float l4[4] = {};

    u16* Pst = &QP[w * 2048];
    u32* Pst32 = (u32*)Pst;
    const int swz_w = (ml >> 1) & 3;

    const u32 kr = tid >> 3, kcc = tid & 7;
    const u32 vd = tid >> 2, vsc = tid & 3;

    u32 kOff = base + kr * D + kcc * 8;
    u32 vOff = vbase + vd * 2048 + vsc * 32;

    for (int it = 0; it < 16; ++it) {
        __syncthreads();
#pragma unroll
        for (int j = 0; j < 4; ++j)
            *(uint4*)&Ks[(kr + j * 32) * 72 + kcc * 8] =
                *(const uint4*)&Kp[kOff + j * 32 * D];
#pragma unroll
        for (int j = 0; j < 4; ++j)
            *(uint4*)&Vts[vd * 136 + vsc * 32 + j * 8] =
                *(const uint4*)&Vt[vOff + j * 8];
        kOff += 128 * D;
        vOff += 128;
        __syncthreads();

#pragma unroll
        for (int hf = 0; hf < 2; ++hf) {
            short8 ka0 = *(const short8*)&Ks[(hf * 64 + w * 16 + ml) * 72 + g * 8];
            short8 ka1 = *(const short8*)&Ks[(hf * 64 + w * 16 + ml) * 72 + 32 + g * 8];
            const int Qd0 = hf * 2 + (g >> 1);
            const u32 pbase = ml * 16 + (u32)(((Qd0 ^ swz_w) << 2) | ((g & 1) << 1));
#pragma unroll
            for (int qt = 0; qt < 4; ++qt) {
                f32x4 z = {};
                z = __builtin_amdgcn_mfma_f32_16x16x32_bf16(ka0, bq[qt][0], z, 0, 0, 0);
                z = __builtin_amdgcn_mfma_f32_16x16x32_bf16(ka1, bq[qt][1], z, 0, 0, 0);
                float p0 = exp2f(z[0]), p1 = exp2f(z[1]);
                float p2 = exp2f(z[2]), p3 = exp2f(z[3]);
                l4[qt] += (p0 + p1) + (p2 + p3);
                Pst32[qt * 256 + pbase]     = pack2(p0, p1);
                Pst32[qt * 256 + pbase + 1] = pack2(p2, p3);
            }
        }

        short8 pb[4];
#pragma unroll
        for (int qt = 0; qt < 4; ++qt) {
            const u32 q = qt * 16 + ml;
            pb[qt] = *(const short8*)&Pst[q * 32 + ((g ^ ((q >> 1) & 3)) * 8)];
        }
#pragma unroll
        for (int dt = 0; dt < 4; ++dt) {
            short8 va = *(const short8*)&Vts[(dt * 16 + ml) * 136 +
                                             (g >> 1) * 64 + w * 16 + (g & 1) * 8];
#pragma unroll
            for (int qt = 0; qt < 4; ++qt)
                oacc[dt][qt] = __builtin_amdgcn_mfma_f32_16x16x32_bf16(
                    va, pb[qt], oacc[dt][qt], 0, 0, 0);
        }
    }

    __syncthreads();
    float* R0 = (float*)pool;
    float* R1 = R0 + 4096;
    float* Lr = R1 + 4096;

#pragma unroll
    for (int qt = 0; qt < 4; ++qt) {
        l4[qt] += __shfl_xor(l4[qt], 16);
        l4[qt] += __shfl_xor(l4[qt], 32);
    }
    if (g == 0) {
#pragma unroll
        for (int qt = 0; qt < 4; ++qt) Lr[w * 64 + qt * 16 + ml] = l4[qt];
    }

#define WRITE_R(Rp)                                                          \
    {_Pragma("unroll") for (int dt = 0; dt < 4; ++dt)                        \
     _Pragma("unroll") for (int qt = 0; qt < 4; ++qt)                        \
     _Pragma("unroll") for (int r = 0; r < 4; ++r)                           \
        (Rp)[(dt * 16 + g * 4 + r) * 64 + qt * 16 + ml] = oacc[dt][qt][r];}
#define ADD_R(Rp)                                                            \
    {_Pragma("unroll") for (int dt = 0; dt < 4; ++dt)                        \
     _Pragma("unroll") for (int qt = 0; qt < 4; ++qt)                        \
     _Pragma("unroll") for (int r = 0; r < 4; ++r)                           \
        oacc[dt][qt][r] += (Rp)[(dt * 16 + g * 4 + r) * 64 + qt * 16 + ml];}

    if (w == 1) WRITE_R(R0)
    if (w == 3) WRITE_R(R1)
    __syncthreads();
    if (w == 0) ADD_R(R0)
    if (w == 2) ADD_R(R1)
    __syncthreads();
    if (w == 2) WRITE_R(R0)
    __syncthreads();
    if (w == 0) {
        ADD_R(R0)
#pragma unroll
        for (int qt = 0; qt < 4; ++qt) {
            const u32 q = qt * 16 + ml;
            const float inv = 1.0f / (Lr[q] + Lr[64 + q] + Lr[128 + q] + Lr[192 + q]);
            const u32 row = (b * T + t0 + q) * D + h * 64;
#pragma unroll
            for (int dt = 0; dt < 4; ++dt) {
                const u32 ci = row + dt * 16 + g * 4;
                *(u32*)&Op[ci]     = pack2(oacc[dt][qt][0] * inv, oacc[dt][qt][1] * inv);
                *(u32*)&Op[ci + 2] = pack2(oacc[dt][qt][2] * inv, oacc[dt][qt][3] * inv);
            }
        }
    }
#undef WRITE_R
#undef ADD_R
}

extern "C" void kernel_launch(void* const* d_in, const int* in_sizes, int n_in,
                              void* d_out, int out_size, void* d_ws, size_t ws_size,
                              hipStream_t stream)
{
    const float* kin = (const float*)d_in[0];
    const float* qin = (const float*)d_in[1];
    const float* vin = (const float*)d_in[2];
    const float* Wk  = (const float*)d_in[3];
    const float* Wq  = (const float*)d_in[4];
    const float* Wv  = (const float*)d_in[5];
    const float* Wo  = (const float*)d_in[6];
    const float* bo  = (const float*)d_in[7];
    float* out = (float*)d_out;

    const size_t ACT = 4194304;   // b*t*d
    const size_t WSZ = 1048576;   // d*d

    u16* kb  = (u16*)d_ws;
    u16* qb  = kb + ACT;
    u16* vb  = qb + ACT;
    u16* Wkb = vb + ACT;
    u16* Wqb = Wkb + WSZ;
    u16* Wvb = Wqb + WSZ;
    u16* Wob = Wvb + WSZ;
    u16* Kp  = Wob + WSZ;
    u16* Qp  = Kp + ACT;
    u16* Vt  = Qp + ACT;
    u16* Op  = kb;   // alias: kb consumed by proj3 before attn writes Op

    convert_kernel<<<dim3(1024, 7), 256, 0, stream>>>(
        kin, qin, vin, Wk, Wq, Wv, Wo, kb, qb, vb, Wkb, Wqb, Wvb, Wob);
    proj3_kernel<<<dim3(8, 32, 3), 256, 0, stream>>>(
        kb, qb, vb, Wkb, Wqb, Wvb, Kp, Qp, Vt);
    attn_kernel<<<dim3(32, 32), 256, 0, stream>>>(Qp, Kp, Vt, Op);
    out_gemm_kernel<<<dim3(8, 32), 256, 0, stream>>>(Op, Wob, out, bo);
}

// Round 7
// 245.944 us; speedup vs baseline: 1.1564x; 1.0787x over previous
//
#include <hip/hip_runtime.h>
#include <hip/hip_bf16.h>

// MHA forward: b=2, t=2048, d=1024, h=16, n=64. Inputs/outputs FLOAT32.
// bf16 internals. ws (u16, 58.7 MB, proven): kb|qb|vb (4194304 ea) |
// Wkb|Wqb|Wvb|Wob (1048576 ea) | Kp|Qp|Vt (4194304 ea) | Op aliases kb.
// Vt = per-head transposed V: [bh][64 d][2048 t], produced DIRECTLY by a
// swapped-operand GEMM (Wv @ v^T) with coalesced stores.
// attn: barrier-free main loop; K/V/Q fragments loaded straight from global.

typedef unsigned short u16;
typedef unsigned int   u32;
using short8 = __attribute__((ext_vector_type(8))) short;
using f32x4  = __attribute__((ext_vector_type(4))) float;

__device__ __forceinline__ u16 f2b(float f) {
    u32 u = __float_as_uint(f);
    u += 0x7FFFu + ((u >> 16) & 1u);
    return (u16)(u >> 16);
}
__device__ __forceinline__ u32 pack2(float lo, float hi) {
    union { __hip_bfloat162 h; u32 u; } c;
    c.h = __float22bfloat162_rn(make_float2(lo, hi));
    return c.u;
}
__device__ __forceinline__ void gld_lds16(const u16* g, u16* l) {
    __builtin_amdgcn_global_load_lds(
        (const __attribute__((address_space(1))) void*)g,
        (__attribute__((address_space(3))) void*)l, 16, 0, 0);
}

// ---------------------------------------------------------------------------
// fp32 -> bf16 convert. grid (1024, 7).
// ---------------------------------------------------------------------------
__global__ __launch_bounds__(256) void convert_kernel(
    const float* s0, const float* s1, const float* s2, const float* s3,
    const float* s4, const float* s5, const float* s6,
    u16* d0, u16* d1, u16* d2, u16* d3, u16* d4, u16* d5, u16* d6)
{
    const int y = blockIdx.y;
    const float* s; u16* d; u32 n;
    switch (y) {
        case 0: s = s0; d = d0; n = 1048576; break;
        case 1: s = s1; d = d1; n = 1048576; break;
        case 2: s = s2; d = d2; n = 1048576; break;
        case 3: s = s3; d = d3; n = 262144; break;
        case 4: s = s4; d = d4; n = 262144; break;
        case 5: s = s5; d = d5; n = 262144; break;
        default: s = s6; d = d6; n = 262144; break;
    }
    for (u32 i = blockIdx.x * 256 + threadIdx.x; i < n; i += 256 * 1024) {
        float4 f = ((const float4*)s)[i];
        uint2 o; o.x = pack2(f.x, f.y); o.y = pack2(f.z, f.w);
        ((uint2*)d)[i] = o;
    }
}

// ---------------------------------------------------------------------------
// GEMM core: C(128x128 tile) = A[m][k] @ B[n][k]^T, K=1024, bf16,
// global_load_lds staging, XOR-swizzled unpadded LDS.
// MODE 0: u16 C row-major N=1024. MODE 2: f32 C row-major N=1024 + bias.
// MODE 3: u16 C = Vt layout (rows m = h*64+d over 1024; cols n = t over 4096;
//         dest = (n>>11)*2097152 + m*2048 + (n&2047)) — coalesced.
// ---------------------------------------------------------------------------
template <int MODE>
__device__ __forceinline__ void gemm_core(
    const u16* __restrict__ A, const u16* __restrict__ B,
    void* __restrict__ C, const float* __restrict__ bias, float scale,
    u32 bm, u32 bn)
{
    constexpr u32 K = 1024;
    __shared__ u16 As[128 * 32];
    __shared__ u16 Bs[128 * 32];

    const int tid  = threadIdx.x;
    const int lane = tid & 63;
    const int w    = tid >> 6;
    const int wr   = w >> 1, wc = w & 1;
    const int ml   = lane & 15, g = lane >> 4;

    f32x4 acc[4][4] = {};

    const u32 srow = w * 32 + (lane >> 2);
    const u32 scol = (u32)(((lane & 3) ^ ((lane >> 3) & 3)) * 8);
    const u16* gA = A + (size_t)(bm + srow) * K + scol;
    const u16* gB = B + (size_t)(bn + srow) * K + scol;
    u16* lA = &As[w * 1024];
    u16* lB = &Bs[w * 1024];

    const u32 fsw = (u32)((g ^ ((ml >> 1) & 3)) * 8);

    for (u32 k0 = 0; k0 < K; k0 += 32) {
        __syncthreads();
        gld_lds16(gA + k0, lA);
        gld_lds16(gA + 16 * K + k0, lA + 512);
        gld_lds16(gB + k0, lB);
        gld_lds16(gB + 16 * K + k0, lB + 512);
        __syncthreads();

        short8 af[4], bf[4];
#pragma unroll
        for (int it = 0; it < 4; ++it)
            af[it] = *(const short8*)&As[(wr * 64 + it * 16 + ml) * 32 + fsw];
#pragma unroll
        for (int ct = 0; ct < 4; ++ct)
            bf[ct] = *(const short8*)&Bs[(wc * 64 + ct * 16 + ml) * 32 + fsw];
#pragma unroll
        for (int it = 0; it < 4; ++it)
#pragma unroll
            for (int ct = 0; ct < 4; ++ct)
                acc[it][ct] = __builtin_amdgcn_mfma_f32_16x16x32_bf16(
                    af[it], bf[ct], acc[it][ct], 0, 0, 0);
    }

    if (MODE == 3) {
#pragma unroll
        for (int ct = 0; ct < 4; ++ct) {
            const u32 col = bn + wc * 64 + ct * 16 + ml;
            u16* dst = (u16*)C + (col >> 11) * 2097152 + (col & 2047);
#pragma unroll
            for (int it = 0; it < 4; ++it) {
                const u32 row = bm + wr * 64 + it * 16 + g * 4;
#pragma unroll
                for (int r = 0; r < 4; ++r)
                    dst[(size_t)(row + r) * 2048] = f2b(acc[it][ct][r]);
            }
        }
    } else {
#pragma unroll
        for (int ct = 0; ct < 4; ++ct) {
            const u32 col = bn + wc * 64 + ct * 16 + ml;
            const float bv = (MODE == 2 && bias) ? bias[col] : 0.0f;
#pragma unroll
            for (int it = 0; it < 4; ++it) {
                const u32 row = bm + wr * 64 + it * 16 + g * 4;
#pragma unroll
                for (int r = 0; r < 4; ++r) {
                    const float v = acc[it][ct][r] * scale + bv;
                    if (MODE == 2) ((float*)C)[(size_t)(row + r) * 1024 + col] = v;
                    else           ((u16*)C)[(size_t)(row + r) * 1024 + col] = f2b(v);
                }
            }
        }
    }
}

// z=0: Kp = kb@Wk^T ; z=1: Qp = qb@Wq^T * 0.125*log2e ; z=2: Vt = Wv @ v^T
__global__ __launch_bounds__(256) void proj3_kernel(
    const u16* kb, const u16* qb, const u16* vb,
    const u16* Wkb, const u16* Wqb, const u16* Wvb,
    u16* Kp, u16* Qp, u16* Vt)
{
    if (blockIdx.z == 0)
        gemm_core<0>(kb, Wkb, Kp, nullptr, 1.0f, blockIdx.y * 128, blockIdx.x * 128);
    else if (blockIdx.z == 1)
        gemm_core<0>(qb, Wqb, Qp, nullptr, 0.18033688011112042f, blockIdx.y * 128, blockIdx.x * 128);
    else
        gemm_core<3>(Wvb, vb, Vt, nullptr, 1.0f, blockIdx.x * 128, blockIdx.y * 128);
}

__global__ __launch_bounds__(256) void out_gemm_kernel(
    const u16* A, const u16* W, float* C, const float* bias)
{
    gemm_core<2>(A, W, C, bias, 1.0f, blockIdx.y * 128, blockIdx.x * 128);
}

// ---------------------------------------------------------------------------
// Flash attention v4: barrier-free main loop. Block = (bh, 64 q), 4 waves.
// Wave w owns s-slice w*32..+31 of each 128-s iter. K/V/Q fragments loaded
// DIRECTLY from global (A-frag of Kp rows, A-frag of Vt rows, B-frag of Qp
// rows) — each element read exactly once per block. Only per-wave P strip
// lives in LDS ([q=64][k=32] u16, chunk XOR-swizzled by (q>>1)&3). No-max
// softmax (exp2, Q pre-scaled). Cross-wave O/l reduction at the end only.
// ---------------------------------------------------------------------------
__global__ __launch_bounds__(256) void attn_kernel(
    const u16* __restrict__ Qp, const u16* __restrict__ Kp,
    const u16* __restrict__ Vt, u16* __restrict__ Op)
{
    __shared__ u16   Ps[4 * 2048];    // per-wave P strips, 16 KB
    __shared__ float R0[4096];        // reduce buffer, 16 KB
    __shared__ float Lr[256];

    const int tid  = threadIdx.x;
    const int lane = tid & 63;
    const int w    = tid >> 6;
    const int ml   = lane & 15;
    const int g    = lane >> 4;
    const u32 bh   = blockIdx.y;
    const u32 b    = bh >> 4, h = bh & 15;
    const u32 t0   = blockIdx.x * 64;

    const u32 base  = b * 2048 * 1024 + h * 64;   // u16 index into Qp/Kp
    const u32 vbase = bh * 64 * 2048;

    // Q B-frags direct from global: B[k=d][n=q], lane q=ml, d-chunk g*8
    short8 bq[4][2];
#pragma unroll
    for (int qt = 0; qt < 4; ++qt) {
        const u16* qr = Qp + base + (t0 + qt * 16 + ml) * 1024 + g * 8;
        bq[qt][0] = *(const short8*)qr;
        bq[qt][1] = *(const short8*)(qr + 32);
    }

    f32x4 oacc[4][4] = {};            // [dt][qt]: O^T[d=dt*16+g*4+r][q=qt*16+ml]
    float l4[4] = {};

    u16* Pw = &Ps[w * 2048];
    u32* Pw32 = (u32*)Pw;

    // wave-slice global offsets
    u32 kOff = base + (w * 32 + ml) * 1024 + g * 8;        // += 128*1024/iter
    u32 vOff = vbase + ml * 2048 + w * 32 + g * 8;         // += 128/iter

    for (int it = 0; it < 16; ++it) {
        // V A-frags early (used after P round-trip): A[m=d][k=s_local]
        short8 va[4];
#pragma unroll
        for (int dt = 0; dt < 4; ++dt)
            va[dt] = *(const short8*)(Vt + vOff + dt * 16 * 2048);

        // QK: two 16-s sub-tiles; A-frag = Kp rows (m=s), B = Q
#pragma unroll
        for (int sub = 0; sub < 2; ++sub) {
            const u16* kp = Kp + kOff + sub * 16 * 1024;
            short8 ka0 = *(const short8*)kp;
            short8 ka1 = *(const short8*)(kp + 32);
            const u32 ch = (u32)(sub * 2 + (g >> 1));
#pragma unroll
            for (int qt = 0; qt < 4; ++qt) {
                f32x4 z = {};
                z = __builtin_amdgcn_mfma_f32_16x16x32_bf16(ka0, bq[qt][0], z, 0, 0, 0);
                z = __builtin_amdgcn_mfma_f32_16x16x32_bf16(ka1, bq[qt][1], z, 0, 0, 0);
                const float p0 = exp2f(z[0]), p1 = exp2f(z[1]);
                const float p2 = exp2f(z[2]), p3 = exp2f(z[3]);
                l4[qt] += (p0 + p1) + (p2 + p3);
                const u32 q = (u32)(qt * 16 + ml);
                const u32 idx = q * 16 + ((ch ^ ((q >> 1) & 3)) << 2) + (g & 1) * 2;
                uint2 pv; pv.x = pack2(p0, p1); pv.y = pack2(p2, p3);
                *(uint2*)&Pw32[idx] = pv;
            }
        }
        kOff += 128 * 1024;
        vOff += 128;

        // P B-frags: B[k=s_local][n=q], k-chunk g (swizzled)
        short8 pb[4];
#pragma unroll
        for (int qt = 0; qt < 4; ++qt) {
            const u32 q = (u32)(qt * 16 + ml);
            pb[qt] = *(const short8*)&Pw[q * 32 + ((g ^ ((q >> 1) & 3)) * 8)];
        }
        // O^T += V^T(slice) @ P^T
#pragma unroll
        for (int dt = 0; dt < 4; ++dt)
#pragma unroll
            for (int qt = 0; qt < 4; ++qt)
                oacc[dt][qt] = __builtin_amdgcn_mfma_f32_16x16x32_bf16(
                    va[dt], pb[qt], oacc[dt][qt], 0, 0, 0);
    }

    // ---- cross-wave reduction (only barriers in the kernel) ----
#pragma unroll
    for (int qt = 0; qt < 4; ++qt) {
        l4[qt] += __shfl_xor(l4[qt], 16);
        l4[qt] += __shfl_xor(l4[qt], 32);
    }
    if (g == 0) {
#pragma unroll
        for (int qt = 0; qt < 4; ++qt) Lr[w * 64 + qt * 16 + ml] = l4[qt];
    }
    __syncthreads();
    float* R1 = (float*)Ps;   // reuse P strips as second reduce buffer

#define WRITE_R(Rp)                                                          \
    {_Pragma("unroll") for (int dt = 0; dt < 4; ++dt)                        \
     _Pragma("unroll") for (int qt = 0; qt < 4; ++qt)                        \
     _Pragma("unroll") for (int r = 0; r < 4; ++r)                           \
        (Rp)[(dt * 16 + g * 4 + r) * 64 + qt * 16 + ml] = oacc[dt][qt][r];}
#define ADD_R(Rp)                                                            \
    {_Pragma("unroll") for (int dt = 0; dt < 4; ++dt)                        \
     _Pragma("unroll") for (int qt = 0; qt < 4; ++qt)                        \
     _Pragma("unroll") for (int r = 0; r < 4; ++r)                           \
        oacc[dt][qt][r] += (Rp)[(dt * 16 + g * 4 + r) * 64 + qt * 16 + ml];}

    if (w == 1) WRITE_R(R0)
    if (w == 3) WRITE_R(R1)
    __syncthreads();
    if (w == 0) ADD_R(R0)
    if (w == 2) ADD_R(R1)
    __syncthreads();
    if (w == 2) WRITE_R(R0)
    __syncthreads();
    if (w == 0) {
        ADD_R(R0)
#pragma unroll
        for (int qt = 0; qt < 4; ++qt) {
            const u32 q = (u32)(qt * 16 + ml);
            const float inv = 1.0f / (Lr[q] + Lr[64 + q] + Lr[128 + q] + Lr[192 + q]);
            const u32 row = (b * 2048 + t0 + q) * 1024 + h * 64;
#pragma unroll
            for (int dt = 0; dt < 4; ++dt) {
                const u32 ci = row + dt * 16 + g * 4;
                *(u32*)&Op[ci]     = pack2(oacc[dt][qt][0] * inv, oacc[dt][qt][1] * inv);
                *(u32*)&Op[ci + 2] = pack2(oacc[dt][qt][2] * inv, oacc[dt][qt][3] * inv);
            }
        }
    }
#undef WRITE_R
#undef ADD_R
}

extern "C" void kernel_launch(void* const* d_in, const int* in_sizes, int n_in,
                              void* d_out, int out_size, void* d_ws, size_t ws_size,
                              hipStream_t stream)
{
    const float* kin = (const float*)d_in[0];
    const float* qin = (const float*)d_in[1];
    const float* vin = (const float*)d_in[2];
    const float* Wk  = (const float*)d_in[3];
    const float* Wq  = (const float*)d_in[4];
    const float* Wv  = (const float*)d_in[5];
    const float* Wo  = (const float*)d_in[6];
    const float* bo  = (const float*)d_in[7];
    float* out = (float*)d_out;

    const size_t ACT = 4194304;
    const size_t WSZ = 1048576;

    u16* kb  = (u16*)d_ws;
    u16* qb  = kb + ACT;
    u16* vb  = qb + ACT;
    u16* Wkb = vb + ACT;
    u16* Wqb = Wkb + WSZ;
    u16* Wvb = Wqb + WSZ;
    u16* Wob = Wvb + WSZ;
    u16* Kp  = Wob + WSZ;
    u16* Qp  = Kp + ACT;
    u16* Vt  = Qp + ACT;
    u16* Op  = kb;   // alias: kb consumed by proj3 before attn writes Op

    convert_kernel<<<dim3(1024, 7), 256, 0, stream>>>(
        kin, qin, vin, Wk, Wq, Wv, Wo, kb, qb, vb, Wkb, Wqb, Wvb, Wob);
    proj3_kernel<<<dim3(8, 32, 3), 256, 0, stream>>>(
        kb, qb, vb, Wkb, Wqb, Wvb, Kp, Qp, Vt);
    attn_kernel<<<dim3(32, 32), 256, 0, stream>>>(Qp, Kp, Vt, Op);
    out_gemm_kernel<<<dim3(8, 32), 256, 0, stream>>>(Op, Wob, out, bo);
}